// Round 5
// baseline (566.929 us; speedup 1.0000x reference)
//
#include <hip/hip_runtime.h>

typedef __bf16 bf16x8 __attribute__((ext_vector_type(8)));
typedef __bf16 bf16x4 __attribute__((ext_vector_type(4)));
typedef float  f32x4  __attribute__((ext_vector_type(4)));

#define MFMA16(a,b,c) __builtin_amdgcn_mfma_f32_16x16x32_bf16((a),(b),(c),0,0,0)

constexpr int B_ = 256, T_ = 200, DM = 2048, DK = 128;
constexpr int VT_STRIDE = 208;      // Vt[b][v][t], t padded 200->208

// ws layout (bytes)
constexpr size_t OFF_W = 0;                       // Wcat bf16 [384][2048] = 1,572,864
constexpr size_t OFF_Q = 1572864;                 // Q bf16 [51200][128] = 13,107,200
constexpr size_t OFF_K = OFF_Q + 13107200;        // K bf16 [51200][128]
constexpr size_t OFF_V = OFF_K + 13107200;        // Vt bf16 [256][128][208] = 13,631,488

// ---------------- weight conversion: Wq|Wk|Wv fp32 -> Wcat bf16 [384][2048] ----------------
__global__ __launch_bounds__(256) void wconv_kernel(const float* __restrict__ Wq,
                                                    const float* __restrict__ Wk,
                                                    const float* __restrict__ Wv,
                                                    __bf16* __restrict__ Wcat) {
  int idx = (blockIdx.x * 256 + threadIdx.x) * 4;   // < 384*2048 = 786432
  int sel = idx >> 18;                              // /262144 -> 0,1,2
  const float* base = (sel == 0) ? Wq : (sel == 1) ? Wk : Wv;
  float4 f = *(const float4*)(base + (idx - (sel << 18)));
  bf16x4 o;
  o[0] = (__bf16)f.x; o[1] = (__bf16)f.y; o[2] = (__bf16)f.z; o[3] = (__bf16)f.w;
  *(bf16x4*)(Wcat + idx) = o;
}

// ---------------- projection GEMM: C[51200][384] = q(fp32->bf16) @ Wcat^T ----------------
// BM=128, BN=384, 512 threads (8 waves, 2m x 4n). NO LDS, NO BARRIERS:
// MFMA fragments are 8 contiguous elements per lane -> load A (fp32, convert in-reg)
// and B (bf16, L2-resident Wcat) fragments straight from global. Each wave free-runs;
// the compiler pipelines loads across k-steps with no phase drain anywhere.
__global__ __launch_bounds__(512) void proj_kernel(const float* __restrict__ q,
                                                   const __bf16* __restrict__ Wcat,
                                                   __bf16* __restrict__ Qo,
                                                   __bf16* __restrict__ Ko,
                                                   __bf16* __restrict__ Vt) {
  const int tid  = threadIdx.x;
  const int lane = tid & 63;
  const int w    = tid >> 6;
  const int wm   = w >> 2, wn = w & 3;
  const int lhi  = lane >> 4, llo = lane & 15;
  const int m0   = blockIdx.x * 128;

  f32x4 acc[4][6];
#pragma unroll
  for (int i = 0; i < 4; ++i)
#pragma unroll
    for (int j = 0; j < 6; ++j) acc[i][j] = {0.f, 0.f, 0.f, 0.f};

  // per-lane fragment base pointers (A-frag row = llo, k-chunk = lhi*8)
  const float*  Abase = q    + (size_t)(m0 + wm * 64 + llo) * DM + lhi * 8;
  const __bf16* Bbase = Wcat + (size_t)(wn * 96 + llo) * DM + lhi * 8;

  for (int k0 = 0; k0 < DM; k0 += 32) {
    bf16x8 bfr[6];
#pragma unroll
    for (int j = 0; j < 6; ++j)
      bfr[j] = *(const bf16x8*)(Bbase + (size_t)j * 16 * DM + k0);

    bf16x8 af[4];
#pragma unroll
    for (int i = 0; i < 4; ++i) {
      const float4* ap = (const float4*)(Abase + (size_t)i * 16 * DM + k0);
      float4 f0 = ap[0], f1 = ap[1];
      af[i][0]=(__bf16)f0.x; af[i][1]=(__bf16)f0.y; af[i][2]=(__bf16)f0.z; af[i][3]=(__bf16)f0.w;
      af[i][4]=(__bf16)f1.x; af[i][5]=(__bf16)f1.y; af[i][6]=(__bf16)f1.z; af[i][7]=(__bf16)f1.w;
    }

#pragma unroll
    for (int i = 0; i < 4; ++i)
#pragma unroll
      for (int j = 0; j < 6; ++j) acc[i][j] = MFMA16(af[i], bfr[j], acc[i][j]);
  }

  // epilogue: col<128 -> Q, <256 -> K, else -> Vt transposed per batch
#pragma unroll
  for (int i = 0; i < 4; ++i) {
#pragma unroll
    for (int r = 0; r < 4; ++r) {
      int row = m0 + wm * 64 + i * 16 + lhi * 4 + r;   // bt index, always < 51200
      int b = row / 200;
      int t = row - b * 200;
#pragma unroll
      for (int j = 0; j < 6; ++j) {
        int col = wn * 96 + j * 16 + llo;
        __bf16 bv = (__bf16)acc[i][j][r];
        if (col < 128)       Qo[(size_t)row * DK + col] = bv;
        else if (col < 256)  Ko[(size_t)row * DK + (col - 128)] = bv;
        else                 Vt[((size_t)b * DK + (col - 256)) * VT_STRIDE + t] = bv;
      }
    }
  }
}

// ---------------- attention: one WG per (batch, 64-query block), templated on block ----------------
template <int QB>
__global__ __launch_bounds__(256, 1) void attn_kernel(const __bf16* __restrict__ Qg,
                                                      const __bf16* __restrict__ Kg,
                                                      const __bf16* __restrict__ Vt,
                                                      const int* __restrict__ padm,
                                                      float* __restrict__ out) {
  constexpr int Q0     = QB * 64;
  constexpr int KMAX   = (Q0 + 64 < T_) ? (Q0 + 64) : T_;   // 64,128,192,200 (causal bound)
  constexpr int KTILES = (KMAX + 15) / 16;                  // 4,8,12,13
  constexpr int KCC    = (KMAX + 31) / 32;                  // 2,4,6,7
  constexpr int KT16   = KTILES * 16;                       // 64,128,192,208
  constexpr int KP     = KCC * 32;                          // 64,128,192,224
  constexpr int VS     = KP + 8;                            // padded stride (bank spread)

  __shared__ __bf16 sK[KT16][136];
  __shared__ __bf16 sV[128][VS];       // V^T: [v][t]
  __shared__ __bf16 sP[4][16][VS];     // per-wave P transpose buffer
  __shared__ float  sMask[KT16];

  const int tid  = threadIdx.x;
  const int lane = tid & 63;
  const int w    = tid >> 6;
  const int b    = blockIdx.x;
  const int lhi  = lane >> 4, llo = lane & 15;

  // additive key mask: 0 valid, -1e30 for pad / t>=KMAX
  for (int t = tid; t < KT16; t += 256) {
    float mv = -1e30f;
    if (t < KMAX && padm[b * T_ + t] == 0) mv = 0.0f;
    sMask[t] = mv;
  }
  // stage K rows [0, KT16) (rows >= T_ clamped; they get masked anyway)
  for (int cid = tid; cid < KT16 * 16; cid += 256) {
    int t = cid >> 4, c = (cid & 15) * 8;
    int tg = (t < T_) ? t : (T_ - 1);
    *(bf16x8*)&sK[t][c] = *(const bf16x8*)(Kg + ((size_t)b * T_ + tg) * DK + c);
  }
  // stage V^T: [128][KP), zeros beyond Vt's 208 columns
  {
    constexpr int NCH = KP / 8;
    for (int cid = tid; cid < 128 * NCH; cid += 256) {
      int v = cid / NCH, t0 = (cid % NCH) * 8;
      bf16x8 val;
      if (t0 < VT_STRIDE) {
        val = *(const bf16x8*)(Vt + ((size_t)b * DK + v) * VT_STRIDE + t0);
      } else {
#pragma unroll
        for (int jz = 0; jz < 8; ++jz) val[jz] = (__bf16)0.0f;
      }
      *(bf16x8*)&sV[v][t0] = val;
    }
  }
  // zero P pad columns [KT16, KP) (only QB==3: 208..224)
  if constexpr (KT16 < KP) {
    constexpr int NC = (KP - KT16) / 8;
    for (int idx = tid; idx < 4 * 16 * NC; idx += 256) {
      int ww = idx / (16 * NC);
      int rem = idx % (16 * NC);
      int row = rem / NC, cc = (rem % NC) * 8;
      bf16x8 z;
#pragma unroll
      for (int jz = 0; jz < 8; ++jz) z[jz] = (__bf16)0.0f;
      *(bf16x8*)&sP[ww][row][KT16 + cc] = z;
    }
  }
  __syncthreads();

  // Q fragments in registers (A-frag: row = llo, k-chunk = lhi)
  const int q0w = Q0 + w * 16;
  bf16x8 qf[4];
  {
    int qrow = q0w + llo;
    if (qrow > T_ - 1) qrow = T_ - 1;
    const __bf16* qp = Qg + ((size_t)b * T_ + qrow) * DK + lhi * 8;
#pragma unroll
    for (int kk = 0; kk < 4; ++kk) qf[kk] = *(const bf16x8*)(qp + kk * 32);
  }

  // scores: S[16q x KT16] per wave, kept in registers
  float sc[KTILES][4];
  const float scale = 0.022097086912079608f;   // 1/sqrt(2048)
#pragma unroll
  for (int tt = 0; tt < KTILES; ++tt) {
    f32x4 s = {0.f, 0.f, 0.f, 0.f};
    const __bf16* kp = &sK[tt * 16 + llo][lhi * 8];
#pragma unroll
    for (int kk = 0; kk < 4; ++kk) {
      bf16x8 kf = *(const bf16x8*)(kp + kk * 32);
      s = MFMA16(qf[kk], kf, s);
    }
    const int t = tt * 16 + llo;
    const float madd = sMask[t];
#pragma unroll
    for (int r = 0; r < 4; ++r) {
      int qq = q0w + lhi * 4 + r;               // C layout: row = lhi*4+r, col = llo
      float v = fmaf(s[r], scale, madd);
      sc[tt][r] = (t > qq) ? -1e30f : v;        // overwrite-style causal mask (NaN-safe)
    }
  }

  // row softmax: reduce across the 16-lane col group per accumulator row
#pragma unroll
  for (int r = 0; r < 4; ++r) {
    float mm = -3e38f;
#pragma unroll
    for (int tt = 0; tt < KTILES; ++tt) mm = fmaxf(mm, sc[tt][r]);
#pragma unroll
    for (int off = 1; off < 16; off <<= 1) mm = fmaxf(mm, __shfl_xor(mm, off));
    float ss = 0.f;
#pragma unroll
    for (int tt = 0; tt < KTILES; ++tt) { float e = __expf(sc[tt][r] - mm); sc[tt][r] = e; ss += e; }
#pragma unroll
    for (int off = 1; off < 16; off <<= 1) ss += __shfl_xor(ss, off);
    float inv = 1.0f / ss;
#pragma unroll
    for (int tt = 0; tt < KTILES; ++tt) sc[tt][r] *= inv;
  }

  // P -> LDS (transpose through memory for the PV A-fragment)
#pragma unroll
  for (int tt = 0; tt < KTILES; ++tt) {
    int t = tt * 16 + llo;
#pragma unroll
    for (int r = 0; r < 4; ++r) sP[w][lhi * 4 + r][t] = (__bf16)sc[tt][r];
  }
  __syncthreads();

  // PV: out[16q x 128v] = P[16 x KP] @ V[KP x 128]
  f32x4 oacc[8];
#pragma unroll
  for (int vt = 0; vt < 8; ++vt) oacc[vt] = {0.f, 0.f, 0.f, 0.f};
#pragma unroll
  for (int kc = 0; kc < KCC; ++kc) {
    bf16x8 pa = *(const bf16x8*)&sP[w][llo][kc * 32 + lhi * 8];
#pragma unroll
    for (int vt = 0; vt < 8; ++vt) {
      bf16x8 vb = *(const bf16x8*)&sV[vt * 16 + llo][kc * 32 + lhi * 8];
      oacc[vt] = MFMA16(pa, vb, oacc[vt]);
    }
  }

  // write fp32 output
#pragma unroll
  for (int vt = 0; vt < 8; ++vt) {
#pragma unroll
    for (int r = 0; r < 4; ++r) {
      int qq = q0w + lhi * 4 + r;
      if (qq < T_) out[((size_t)b * T_ + qq) * DK + vt * 16 + llo] = oacc[vt][r];
    }
  }
}

extern "C" void kernel_launch(void* const* d_in, const int* in_sizes, int n_in,
                              void* d_out, int out_size, void* d_ws, size_t ws_size,
                              hipStream_t stream) {
  const float* q    = (const float*)d_in[0];
  const int*   padm = (const int*)d_in[1];
  const float* Wq   = (const float*)d_in[2];
  const float* Wk   = (const float*)d_in[3];
  const float* Wv   = (const float*)d_in[4];
  float* out        = (float*)d_out;

  char* ws = (char*)d_ws;
  __bf16* Wcat = (__bf16*)(ws + OFF_W);
  __bf16* Qb   = (__bf16*)(ws + OFF_Q);
  __bf16* Kb   = (__bf16*)(ws + OFF_K);
  __bf16* Vtb  = (__bf16*)(ws + OFF_V);

  wconv_kernel<<<768, 256, 0, stream>>>(Wq, Wk, Wv, Wcat);
  proj_kernel<<<400, 512, 0, stream>>>(q, Wcat, Qb, Kb, Vtb);
  attn_kernel<0><<<256, 256, 0, stream>>>(Qb, Kb, Vtb, padm, out);
  attn_kernel<1><<<256, 256, 0, stream>>>(Qb, Kb, Vtb, padm, out);
  attn_kernel<2><<<256, 256, 0, stream>>>(Qb, Kb, Vtb, padm, out);
  attn_kernel<3><<<256, 256, 0, stream>>>(Qb, Kb, Vtb, padm, out);
}

// Round 6
// 287.721 us; speedup vs baseline: 1.9704x; 1.9704x over previous
//
#include <hip/hip_runtime.h>

typedef __bf16 bf16x8 __attribute__((ext_vector_type(8)));
typedef __bf16 bf16x4 __attribute__((ext_vector_type(4)));
typedef float  f32x4  __attribute__((ext_vector_type(4)));

#define MFMA16(a,b,c) __builtin_amdgcn_mfma_f32_16x16x32_bf16((a),(b),(c),0,0,0)

constexpr int B_ = 256, T_ = 200, DM = 2048, DK = 128;
constexpr int VT_STRIDE = 208;      // Vt[b][v][t], t padded 200->208

// ws layout (bytes)
constexpr size_t OFF_W = 0;                       // Wcat bf16 [384][2048] = 1,572,864
constexpr size_t OFF_Q = 1572864;                 // Q bf16 [51200][128] = 13,107,200
constexpr size_t OFF_K = OFF_Q + 13107200;        // K bf16 [51200][128]
constexpr size_t OFF_V = OFF_K + 13107200;        // Vt bf16 [256][128][208] = 13,631,488

#define GLOAD_LDS16(G, L)                                                     \
  __builtin_amdgcn_global_load_lds(                                           \
      (const __attribute__((address_space(1))) void*)(G),                     \
      (__attribute__((address_space(3))) void*)(L), 16, 0, 0)

// ---------------- weight conversion: Wq|Wk|Wv fp32 -> Wcat bf16 [384][2048] ----------------
__global__ __launch_bounds__(256) void wconv_kernel(const float* __restrict__ Wq,
                                                    const float* __restrict__ Wk,
                                                    const float* __restrict__ Wv,
                                                    __bf16* __restrict__ Wcat) {
  int idx = (blockIdx.x * 256 + threadIdx.x) * 4;   // < 384*2048 = 786432
  int sel = idx >> 18;                              // /262144 -> 0,1,2
  const float* base = (sel == 0) ? Wq : (sel == 1) ? Wk : Wv;
  float4 f = *(const float4*)(base + (idx - (sel << 18)));
  bf16x4 o;
  o[0] = (__bf16)f.x; o[1] = (__bf16)f.y; o[2] = (__bf16)f.z; o[3] = (__bf16)f.w;
  *(bf16x4*)(Wcat + idx) = o;
}

// ---------------- projection GEMM: C[51200][384] = q(fp32->bf16) @ Wcat^T ----------------
// BM=32, BN=384 (full N -> q HBM-read exactly once), BK=64, 256 threads (4 waves, 1m x 4n,
// wave tile 32x96, acc=48 AGPR). global_load_lds dwordx4 staging for A (fp32, converted at
// frag read) and B (bf16). XOR-swizzled LDS via pre-swizzled global source (both-sides rule):
//   A slot(row, cs) holds global chunk cs^(row&15); B slot(row, cs) holds cs^(row&7).
// Frag reads apply the same XOR -> 2-way bank aliasing (free). 56 KiB LDS, ~110 VGPR ->
// 2 blocks/CU resident; the second block hides the vmcnt(0)+barrier stage drain (m97/m114).
__global__ __launch_bounds__(256) void proj_kernel(const float* __restrict__ q,
                                                   const __bf16* __restrict__ Wcat,
                                                   __bf16* __restrict__ Qo,
                                                   __bf16* __restrict__ Ko,
                                                   __bf16* __restrict__ Vt) {
  __shared__ alignas(16) char smem[57344];   // A fp32 [32][64] = 8192 B, B bf16 [384][64] = 49152 B
  char* const ldsA = smem;
  char* const ldsB = smem + 8192;

  const int tid  = threadIdx.x;
  const int lane = tid & 63;
  const int wn   = tid >> 6;                 // 4 waves across N
  const int lhi  = lane >> 4, llo = lane & 15;
  const int m0   = blockIdx.x * 32;

  f32x4 acc[2][6];
#pragma unroll
  for (int i = 0; i < 2; ++i)
#pragma unroll
    for (int j = 0; j < 6; ++j) acc[i][j] = {0.f, 0.f, 0.f, 0.f};

  // A staging (2 rounds of 16 rows): row = r*16 + (tid>>4); slot cs = tid&15;
  // global chunk c = cs ^ (row&15) = (tid&15) ^ (tid>>4)   (round-invariant)
  const int arow = tid >> 4;
  const int acnk = (tid & 15) ^ arow;
  const float* agbase = q + (size_t)(m0 + arow) * DM + acnk * 4;
  // B staging (12 rounds of 32 rows): row = r*32 + (tid>>3); cs = tid&7;
  // c = cs ^ ((tid>>3)&7)   (round-invariant)
  const int brow = tid >> 3;
  const int bcnk = (tid & 7) ^ (brow & 7);
  const __bf16* bgbase = Wcat + (size_t)brow * DM + bcnk * 8;

#define STAGE(K0)                                                             \
  {                                                                           \
    _Pragma("unroll")                                                         \
    for (int r = 0; r < 2; ++r)                                               \
      GLOAD_LDS16(agbase + (size_t)r * 16 * DM + (K0),                        \
                  ldsA + r * 4096 + tid * 16);                                \
    _Pragma("unroll")                                                         \
    for (int r = 0; r < 12; ++r)                                              \
      GLOAD_LDS16(bgbase + (size_t)r * 32 * DM + (K0),                        \
                  ldsB + r * 4096 + tid * 16);                                \
  }

  constexpr int NK = DM / 64;   // 32 K-steps
  STAGE(0);
  __syncthreads();              // vmcnt(0)+lgkmcnt(0) drain + barrier: tile 0 ready

  for (int it = 0; it < NK; ++it) {
#pragma unroll
    for (int kk = 0; kk < 2; ++kk) {
      // A frags: row = i*16+llo (row&15 == llo); chunks c0 = kk*8+lhi*2, c0+1
      bf16x8 af[2];
#pragma unroll
      for (int i = 0; i < 2; ++i) {
        const int row = i * 16 + llo;
        const int c0 = kk * 8 + lhi * 2;
        f32x4 u = *(const f32x4*)(ldsA + row * 256 + ((c0 ^ llo) & 15) * 16);
        f32x4 v = *(const f32x4*)(ldsA + row * 256 + (((c0 + 1) ^ llo) & 15) * 16);
        af[i][0]=(__bf16)u[0]; af[i][1]=(__bf16)u[1]; af[i][2]=(__bf16)u[2]; af[i][3]=(__bf16)u[3];
        af[i][4]=(__bf16)v[0]; af[i][5]=(__bf16)v[1]; af[i][6]=(__bf16)v[2]; af[i][7]=(__bf16)v[3];
      }
      // B frags: row = wn*96 + j*16 + llo (row&7 == llo&7); chunk c = kk*4+lhi
      bf16x8 bfr[6];
#pragma unroll
      for (int j = 0; j < 6; ++j) {
        const int row = wn * 96 + j * 16 + llo;
        const int c = kk * 4 + lhi;
        bfr[j] = *(const bf16x8*)(ldsB + row * 128 + ((c ^ (llo & 7)) & 7) * 16);
      }
#pragma unroll
      for (int i = 0; i < 2; ++i)
#pragma unroll
        for (int j = 0; j < 6; ++j) acc[i][j] = MFMA16(af[i], bfr[j], acc[i][j]);
    }
    __syncthreads();            // compute done before overwrite
    if (it + 1 < NK) {
      STAGE((it + 1) * 64);
      __syncthreads();          // next tile ready
    }
  }
#undef STAGE

  // epilogue: col<128 -> Q, <256 -> K, else -> Vt transposed per batch
#pragma unroll
  for (int i = 0; i < 2; ++i) {
#pragma unroll
    for (int r = 0; r < 4; ++r) {
      int row = m0 + i * 16 + lhi * 4 + r;   // bt index, always < 51200
      int b = row / 200;
      int t = row - b * 200;
#pragma unroll
      for (int j = 0; j < 6; ++j) {
        int col = wn * 96 + j * 16 + llo;
        __bf16 bv = (__bf16)acc[i][j][r];
        if (col < 128)       Qo[(size_t)row * DK + col] = bv;
        else if (col < 256)  Ko[(size_t)row * DK + (col - 128)] = bv;
        else                 Vt[((size_t)b * DK + (col - 256)) * VT_STRIDE + t] = bv;
      }
    }
  }
}

// ---------------- attention: one WG per (batch, 64-query block), templated on block ----------------
template <int QB>
__global__ __launch_bounds__(256, 1) void attn_kernel(const __bf16* __restrict__ Qg,
                                                      const __bf16* __restrict__ Kg,
                                                      const __bf16* __restrict__ Vt,
                                                      const int* __restrict__ padm,
                                                      float* __restrict__ out) {
  constexpr int Q0     = QB * 64;
  constexpr int KMAX   = (Q0 + 64 < T_) ? (Q0 + 64) : T_;   // 64,128,192,200 (causal bound)
  constexpr int KTILES = (KMAX + 15) / 16;                  // 4,8,12,13
  constexpr int KCC    = (KMAX + 31) / 32;                  // 2,4,6,7
  constexpr int KT16   = KTILES * 16;                       // 64,128,192,208
  constexpr int KP     = KCC * 32;                          // 64,128,192,224
  constexpr int VS     = KP + 8;                            // padded stride (bank spread)

  __shared__ __bf16 sK[KT16][136];
  __shared__ __bf16 sV[128][VS];       // V^T: [v][t]
  __shared__ __bf16 sP[4][16][VS];     // per-wave P transpose buffer
  __shared__ float  sMask[KT16];

  const int tid  = threadIdx.x;
  const int lane = tid & 63;
  const int w    = tid >> 6;
  const int b    = blockIdx.x;
  const int lhi  = lane >> 4, llo = lane & 15;

  // additive key mask: 0 valid, -1e30 for pad / t>=KMAX
  for (int t = tid; t < KT16; t += 256) {
    float mv = -1e30f;
    if (t < KMAX && padm[b * T_ + t] == 0) mv = 0.0f;
    sMask[t] = mv;
  }
  // stage K rows [0, KT16) (rows >= T_ clamped; they get masked anyway)
  for (int cid = tid; cid < KT16 * 16; cid += 256) {
    int t = cid >> 4, c = (cid & 15) * 8;
    int tg = (t < T_) ? t : (T_ - 1);
    *(bf16x8*)&sK[t][c] = *(const bf16x8*)(Kg + ((size_t)b * T_ + tg) * DK + c);
  }
  // stage V^T: [128][KP), zeros beyond Vt's 208 columns
  {
    constexpr int NCH = KP / 8;
    for (int cid = tid; cid < 128 * NCH; cid += 256) {
      int v = cid / NCH, t0 = (cid % NCH) * 8;
      bf16x8 val;
      if (t0 < VT_STRIDE) {
        val = *(const bf16x8*)(Vt + ((size_t)b * DK + v) * VT_STRIDE + t0);
      } else {
#pragma unroll
        for (int jz = 0; jz < 8; ++jz) val[jz] = (__bf16)0.0f;
      }
      *(bf16x8*)&sV[v][t0] = val;
    }
  }
  // zero P pad columns [KT16, KP) (only QB==3: 208..224)
  if constexpr (KT16 < KP) {
    constexpr int NC = (KP - KT16) / 8;
    for (int idx = tid; idx < 4 * 16 * NC; idx += 256) {
      int ww = idx / (16 * NC);
      int rem = idx % (16 * NC);
      int row = rem / NC, cc = (rem % NC) * 8;
      bf16x8 z;
#pragma unroll
      for (int jz = 0; jz < 8; ++jz) z[jz] = (__bf16)0.0f;
      *(bf16x8*)&sP[ww][row][KT16 + cc] = z;
    }
  }
  __syncthreads();

  // Q fragments in registers (A-frag: row = llo, k-chunk = lhi)
  const int q0w = Q0 + w * 16;
  bf16x8 qf[4];
  {
    int qrow = q0w + llo;
    if (qrow > T_ - 1) qrow = T_ - 1;
    const __bf16* qp = Qg + ((size_t)b * T_ + qrow) * DK + lhi * 8;
#pragma unroll
    for (int kk = 0; kk < 4; ++kk) qf[kk] = *(const bf16x8*)(qp + kk * 32);
  }

  // scores: S[16q x KT16] per wave, kept in registers
  float sc[KTILES][4];
  const float scale = 0.022097086912079608f;   // 1/sqrt(2048)
#pragma unroll
  for (int tt = 0; tt < KTILES; ++tt) {
    f32x4 s = {0.f, 0.f, 0.f, 0.f};
    const __bf16* kp = &sK[tt * 16 + llo][lhi * 8];
#pragma unroll
    for (int kk = 0; kk < 4; ++kk) {
      bf16x8 kf = *(const bf16x8*)(kp + kk * 32);
      s = MFMA16(qf[kk], kf, s);
    }
    const int t = tt * 16 + llo;
    const float madd = sMask[t];
#pragma unroll
    for (int r = 0; r < 4; ++r) {
      int qq = q0w + lhi * 4 + r;               // C layout: row = lhi*4+r, col = llo
      float v = fmaf(s[r], scale, madd);
      sc[tt][r] = (t > qq) ? -1e30f : v;        // overwrite-style causal mask (NaN-safe)
    }
  }

  // row softmax: reduce across the 16-lane col group per accumulator row
#pragma unroll
  for (int r = 0; r < 4; ++r) {
    float mm = -3e38f;
#pragma unroll
    for (int tt = 0; tt < KTILES; ++tt) mm = fmaxf(mm, sc[tt][r]);
#pragma unroll
    for (int off = 1; off < 16; off <<= 1) mm = fmaxf(mm, __shfl_xor(mm, off));
    float ss = 0.f;
#pragma unroll
    for (int tt = 0; tt < KTILES; ++tt) { float e = __expf(sc[tt][r] - mm); sc[tt][r] = e; ss += e; }
#pragma unroll
    for (int off = 1; off < 16; off <<= 1) ss += __shfl_xor(ss, off);
    float inv = 1.0f / ss;
#pragma unroll
    for (int tt = 0; tt < KTILES; ++tt) sc[tt][r] *= inv;
  }

  // P -> LDS (transpose through memory for the PV A-fragment)
#pragma unroll
  for (int tt = 0; tt < KTILES; ++tt) {
    int t = tt * 16 + llo;
#pragma unroll
    for (int r = 0; r < 4; ++r) sP[w][lhi * 4 + r][t] = (__bf16)sc[tt][r];
  }
  __syncthreads();

  // PV: out[16q x 128v] = P[16 x KP] @ V[KP x 128]
  f32x4 oacc[8];
#pragma unroll
  for (int vt = 0; vt < 8; ++vt) oacc[vt] = {0.f, 0.f, 0.f, 0.f};
#pragma unroll
  for (int kc = 0; kc < KCC; ++kc) {
    bf16x8 pa = *(const bf16x8*)&sP[w][llo][kc * 32 + lhi * 8];
#pragma unroll
    for (int vt = 0; vt < 8; ++vt) {
      bf16x8 vb = *(const bf16x8*)&sV[vt * 16 + llo][kc * 32 + lhi * 8];
      oacc[vt] = MFMA16(pa, vb, oacc[vt]);
    }
  }

  // write fp32 output
#pragma unroll
  for (int vt = 0; vt < 8; ++vt) {
#pragma unroll
    for (int r = 0; r < 4; ++r) {
      int qq = q0w + lhi * 4 + r;
      if (qq < T_) out[((size_t)b * T_ + qq) * DK + vt * 16 + llo] = oacc[vt][r];
    }
  }
}

extern "C" void kernel_launch(void* const* d_in, const int* in_sizes, int n_in,
                              void* d_out, int out_size, void* d_ws, size_t ws_size,
                              hipStream_t stream) {
  const float* q    = (const float*)d_in[0];
  const int*   padm = (const int*)d_in[1];
  const float* Wq   = (const float*)d_in[2];
  const float* Wk   = (const float*)d_in[3];
  const float* Wv   = (const float*)d_in[4];
  float* out        = (float*)d_out;

  char* ws = (char*)d_ws;
  __bf16* Wcat = (__bf16*)(ws + OFF_W);
  __bf16* Qb   = (__bf16*)(ws + OFF_Q);
  __bf16* Kb   = (__bf16*)(ws + OFF_K);
  __bf16* Vtb  = (__bf16*)(ws + OFF_V);

  wconv_kernel<<<768, 256, 0, stream>>>(Wq, Wk, Wv, Wcat);
  proj_kernel<<<1600, 256, 0, stream>>>(q, Wcat, Qb, Kb, Vtb);
  attn_kernel<0><<<256, 256, 0, stream>>>(Qb, Kb, Vtb, padm, out);
  attn_kernel<1><<<256, 256, 0, stream>>>(Qb, Kb, Vtb, padm, out);
  attn_kernel<2><<<256, 256, 0, stream>>>(Qb, Kb, Vtb, padm, out);
  attn_kernel<3><<<256, 256, 0, stream>>>(Qb, Kb, Vtb, padm, out);
}

// Round 7
// 259.800 us; speedup vs baseline: 2.1822x; 1.1075x over previous
//
#include <hip/hip_runtime.h>

typedef __bf16 bf16x8 __attribute__((ext_vector_type(8)));
typedef __bf16 bf16x4 __attribute__((ext_vector_type(4)));
typedef float  f32x4  __attribute__((ext_vector_type(4)));

#define MFMA16(a,b,c) __builtin_amdgcn_mfma_f32_16x16x32_bf16((a),(b),(c),0,0,0)

constexpr int B_ = 256, T_ = 200, DM = 2048, DK = 128;
constexpr int VT_STRIDE = 208;      // Vt[b][v][t], t padded 200->208

// ws layout (bytes)
constexpr size_t OFF_W = 0;                       // Wcat bf16 [384][2048] = 1,572,864
constexpr size_t OFF_Q = 1572864;                 // Q bf16 [51200][128] = 13,107,200
constexpr size_t OFF_K = OFF_Q + 13107200;        // K bf16 [51200][128]
constexpr size_t OFF_V = OFF_K + 13107200;        // Vt bf16 [256][128][208] = 13,631,488

#define GLOAD_LDS16(G, L)                                                     \
  __builtin_amdgcn_global_load_lds(                                           \
      (const __attribute__((address_space(1))) void*)(G),                     \
      (__attribute__((address_space(3))) void*)(L), 16, 0, 0)

// ---------------- weight conversion: Wq|Wk|Wv fp32 -> Wcat bf16 [384][2048] ----------------
__global__ __launch_bounds__(256) void wconv_kernel(const float* __restrict__ Wq,
                                                    const float* __restrict__ Wk,
                                                    const float* __restrict__ Wv,
                                                    __bf16* __restrict__ Wcat) {
  int idx = (blockIdx.x * 256 + threadIdx.x) * 4;   // < 384*2048 = 786432
  int sel = idx >> 18;                              // /262144 -> 0,1,2
  const float* base = (sel == 0) ? Wq : (sel == 1) ? Wk : Wv;
  float4 f = *(const float4*)(base + (idx - (sel << 18)));
  bf16x4 o;
  o[0] = (__bf16)f.x; o[1] = (__bf16)f.y; o[2] = (__bf16)f.z; o[3] = (__bf16)f.w;
  *(bf16x4*)(Wcat + idx) = o;
}

// ---------------- projection GEMM: C[51200][384] = q(fp32->bf16) @ Wcat^T ----------------
// BM=64, BN=384 (full N -> q HBM-read exactly once), BK=32, 256 threads (4 waves 1m x 4n,
// wave tile 64x96, acc=96 AGPR). m97 2-barrier template: per K-step issue the 8
// global_load_lds for tile t+1 into buf^1 FIRST, then ds_read+MFMA tile t from buf, then
// ONE __syncthreads() (its vmcnt(0) drain lands after the loads flew across the compute
// phase). 64 KiB dbuf LDS + ~180 regs -> 2 blocks/CU; the co-resident block hides the
// residual drain (m114). Both-sides XOR swizzle (rule #21): A slot c^(row&7), B slot
// kc^((row>>1)&3) -> all frag reads 2-way (free), stage writes linear.
__global__ __launch_bounds__(256) void proj_kernel(const float* __restrict__ q,
                                                   const __bf16* __restrict__ Wcat,
                                                   __bf16* __restrict__ Qo,
                                                   __bf16* __restrict__ Ko,
                                                   __bf16* __restrict__ Vt) {
  __shared__ alignas(16) char smem[65536];   // per buf: A fp32 [64][32] 8 KB @0, B bf16 [384][32] 24 KB @8192

  const int tid  = threadIdx.x;
  const int lane = tid & 63;
  const int wn   = tid >> 6;                 // 4 waves across N
  const int lhi  = lane >> 4, llo = lane & 15;
  const int m0   = blockIdx.x * 64;

  f32x4 acc[4][6];
#pragma unroll
  for (int i = 0; i < 4; ++i)
#pragma unroll
    for (int j = 0; j < 6; ++j) acc[i][j] = {0.f, 0.f, 0.f, 0.f};

  // A staging: 2 rounds of 32 rows; slot s=tid+256r -> row=(tid>>3)+32r, slot-chunk cs=tid&7,
  // global chunk = cs ^ (row&7) = (tid&7)^((tid>>3)&7)  (round-invariant)
  const float* agbase = q + (size_t)(m0 + (tid >> 3)) * DM
                          + (((tid & 7) ^ ((tid >> 3) & 7)) << 2);
  // B staging: 6 rounds of 64 rows; s=tid+256r -> row=(tid>>2)+64r, slot kc=tid&3,
  // global kc = (tid&3) ^ ((row>>1)&3) = (tid&3)^((tid>>3)&3)  (round-invariant)
  const __bf16* bgbase = Wcat + (size_t)(tid >> 2) * DM
                              + (((tid & 3) ^ ((tid >> 3) & 3)) << 3);

#define STAGE(BUF, K0)                                                        \
  {                                                                           \
    char* la = smem + (BUF) * 32768;                                          \
    char* lb = la + 8192;                                                     \
    _Pragma("unroll")                                                         \
    for (int r = 0; r < 2; ++r)                                               \
      GLOAD_LDS16(agbase + (size_t)r * 32 * DM + (K0), la + tid * 16 + r * 4096); \
    _Pragma("unroll")                                                         \
    for (int r = 0; r < 6; ++r)                                               \
      GLOAD_LDS16(bgbase + (size_t)r * 64 * DM + (K0), lb + tid * 16 + r * 4096); \
  }

#define COMPUTE(BUF)                                                          \
  {                                                                           \
    const char* la = smem + (BUF) * 32768;                                    \
    const char* lb = la + 8192;                                               \
    bf16x8 af[4];                                                             \
    _Pragma("unroll")                                                         \
    for (int i = 0; i < 4; ++i) {                                             \
      const int row = i * 16 + llo;                                           \
      f32x4 u = *(const f32x4*)(la + row * 128 + (((2 * lhi) ^ (llo & 7)) << 4));     \
      f32x4 v = *(const f32x4*)(la + row * 128 + (((2 * lhi + 1) ^ (llo & 7)) << 4)); \
      af[i][0]=(__bf16)u[0]; af[i][1]=(__bf16)u[1]; af[i][2]=(__bf16)u[2]; af[i][3]=(__bf16)u[3]; \
      af[i][4]=(__bf16)v[0]; af[i][5]=(__bf16)v[1]; af[i][6]=(__bf16)v[2]; af[i][7]=(__bf16)v[3]; \
    }                                                                         \
    bf16x8 bfr[6];                                                            \
    _Pragma("unroll")                                                         \
    for (int j = 0; j < 6; ++j) {                                             \
      const int row = wn * 96 + j * 16 + llo;                                 \
      bfr[j] = *(const bf16x8*)(lb + row * 64 + ((lhi ^ ((llo >> 1) & 3)) << 4)); \
    }                                                                         \
    _Pragma("unroll")                                                         \
    for (int i = 0; i < 4; ++i)                                               \
      _Pragma("unroll")                                                       \
      for (int j = 0; j < 6; ++j) acc[i][j] = MFMA16(af[i], bfr[j], acc[i][j]); \
  }

  constexpr int NK = DM / 32;   // 64 K-steps
  STAGE(0, 0);
  __syncthreads();              // tile 0 landed

  int buf = 0;
  for (int it = 0; it < NK; ++it) {
    if (it + 1 < NK) STAGE(buf ^ 1, (it + 1) * 32);   // issue FIRST; flies across compute
    COMPUTE(buf);
    __syncthreads();            // single barrier: publishes t+1, protects buf reuse
    buf ^= 1;
  }
#undef STAGE
#undef COMPUTE

  // epilogue: col<128 -> Q, <256 -> K, else -> Vt transposed per batch
#pragma unroll
  for (int i = 0; i < 4; ++i) {
#pragma unroll
    for (int r = 0; r < 4; ++r) {
      int row = m0 + i * 16 + lhi * 4 + r;   // bt index, always < 51200
      int b = row / 200;
      int t = row - b * 200;
#pragma unroll
      for (int j = 0; j < 6; ++j) {
        int col = wn * 96 + j * 16 + llo;
        __bf16 bv = (__bf16)acc[i][j][r];
        if (col < 128)       Qo[(size_t)row * DK + col] = bv;
        else if (col < 256)  Ko[(size_t)row * DK + (col - 128)] = bv;
        else                 Vt[((size_t)b * DK + (col - 256)) * VT_STRIDE + t] = bv;
      }
    }
  }
}

// ---------------- attention: one WG per (batch, 64-query block), templated on block ----------------
template <int QB>
__global__ __launch_bounds__(256, 1) void attn_kernel(const __bf16* __restrict__ Qg,
                                                      const __bf16* __restrict__ Kg,
                                                      const __bf16* __restrict__ Vt,
                                                      const int* __restrict__ padm,
                                                      float* __restrict__ out) {
  constexpr int Q0     = QB * 64;
  constexpr int KMAX   = (Q0 + 64 < T_) ? (Q0 + 64) : T_;   // 64,128,192,200 (causal bound)
  constexpr int KTILES = (KMAX + 15) / 16;                  // 4,8,12,13
  constexpr int KCC    = (KMAX + 31) / 32;                  // 2,4,6,7
  constexpr int KT16   = KTILES * 16;                       // 64,128,192,208
  constexpr int KP     = KCC * 32;                          // 64,128,192,224
  constexpr int VS     = KP + 8;                            // padded stride (bank spread)

  __shared__ __bf16 sK[KT16][136];
  __shared__ __bf16 sV[128][VS];       // V^T: [v][t]
  __shared__ __bf16 sP[4][16][VS];     // per-wave P transpose buffer
  __shared__ float  sMask[KT16];

  const int tid  = threadIdx.x;
  const int lane = tid & 63;
  const int w    = tid >> 6;
  const int b    = blockIdx.x;
  const int lhi  = lane >> 4, llo = lane & 15;

  // additive key mask: 0 valid, -1e30 for pad / t>=KMAX
  for (int t = tid; t < KT16; t += 256) {
    float mv = -1e30f;
    if (t < KMAX && padm[b * T_ + t] == 0) mv = 0.0f;
    sMask[t] = mv;
  }
  // stage K rows [0, KT16) (rows >= T_ clamped; they get masked anyway)
  for (int cid = tid; cid < KT16 * 16; cid += 256) {
    int t = cid >> 4, c = (cid & 15) * 8;
    int tg = (t < T_) ? t : (T_ - 1);
    *(bf16x8*)&sK[t][c] = *(const bf16x8*)(Kg + ((size_t)b * T_ + tg) * DK + c);
  }
  // stage V^T: [128][KP), zeros beyond Vt's 208 columns
  {
    constexpr int NCH = KP / 8;
    for (int cid = tid; cid < 128 * NCH; cid += 256) {
      int v = cid / NCH, t0 = (cid % NCH) * 8;
      bf16x8 val;
      if (t0 < VT_STRIDE) {
        val = *(const bf16x8*)(Vt + ((size_t)b * DK + v) * VT_STRIDE + t0);
      } else {
#pragma unroll
        for (int jz = 0; jz < 8; ++jz) val[jz] = (__bf16)0.0f;
      }
      *(bf16x8*)&sV[v][t0] = val;
    }
  }
  // zero P pad columns [KT16, KP) (only QB==3: 208..224)
  if constexpr (KT16 < KP) {
    constexpr int NC = (KP - KT16) / 8;
    for (int idx = tid; idx < 4 * 16 * NC; idx += 256) {
      int ww = idx / (16 * NC);
      int rem = idx % (16 * NC);
      int row = rem / NC, cc = (rem % NC) * 8;
      bf16x8 z;
#pragma unroll
      for (int jz = 0; jz < 8; ++jz) z[jz] = (__bf16)0.0f;
      *(bf16x8*)&sP[ww][row][KT16 + cc] = z;
    }
  }
  __syncthreads();

  // Q fragments in registers (A-frag: row = llo, k-chunk = lhi)
  const int q0w = Q0 + w * 16;
  bf16x8 qf[4];
  {
    int qrow = q0w + llo;
    if (qrow > T_ - 1) qrow = T_ - 1;
    const __bf16* qp = Qg + ((size_t)b * T_ + qrow) * DK + lhi * 8;
#pragma unroll
    for (int kk = 0; kk < 4; ++kk) qf[kk] = *(const bf16x8*)(qp + kk * 32);
  }

  // scores: S[16q x KT16] per wave, kept in registers
  float sc[KTILES][4];
  const float scale = 0.022097086912079608f;   // 1/sqrt(2048)
#pragma unroll
  for (int tt = 0; tt < KTILES; ++tt) {
    f32x4 s = {0.f, 0.f, 0.f, 0.f};
    const __bf16* kp = &sK[tt * 16 + llo][lhi * 8];
#pragma unroll
    for (int kk = 0; kk < 4; ++kk) {
      bf16x8 kf = *(const bf16x8*)(kp + kk * 32);
      s = MFMA16(qf[kk], kf, s);
    }
    const int t = tt * 16 + llo;
    const float madd = sMask[t];
#pragma unroll
    for (int r = 0; r < 4; ++r) {
      int qq = q0w + lhi * 4 + r;               // C layout: row = lhi*4+r, col = llo
      float v = fmaf(s[r], scale, madd);
      sc[tt][r] = (t > qq) ? -1e30f : v;        // overwrite-style causal mask (NaN-safe)
    }
  }

  // row softmax: reduce across the 16-lane col group per accumulator row
#pragma unroll
  for (int r = 0; r < 4; ++r) {
    float mm = -3e38f;
#pragma unroll
    for (int tt = 0; tt < KTILES; ++tt) mm = fmaxf(mm, sc[tt][r]);
#pragma unroll
    for (int off = 1; off < 16; off <<= 1) mm = fmaxf(mm, __shfl_xor(mm, off));
    float ss = 0.f;
#pragma unroll
    for (int tt = 0; tt < KTILES; ++tt) { float e = __expf(sc[tt][r] - mm); sc[tt][r] = e; ss += e; }
#pragma unroll
    for (int off = 1; off < 16; off <<= 1) ss += __shfl_xor(ss, off);
    float inv = 1.0f / ss;
#pragma unroll
    for (int tt = 0; tt < KTILES; ++tt) sc[tt][r] *= inv;
  }

  // P -> LDS (transpose through memory for the PV A-fragment)
#pragma unroll
  for (int tt = 0; tt < KTILES; ++tt) {
    int t = tt * 16 + llo;
#pragma unroll
    for (int r = 0; r < 4; ++r) sP[w][lhi * 4 + r][t] = (__bf16)sc[tt][r];
  }
  __syncthreads();

  // PV: out[16q x 128v] = P[16 x KP] @ V[KP x 128]
  f32x4 oacc[8];
#pragma unroll
  for (int vt = 0; vt < 8; ++vt) oacc[vt] = {0.f, 0.f, 0.f, 0.f};
#pragma unroll
  for (int kc = 0; kc < KCC; ++kc) {
    bf16x8 pa = *(const bf16x8*)&sP[w][llo][kc * 32 + lhi * 8];
#pragma unroll
    for (int vt = 0; vt < 8; ++vt) {
      bf16x8 vb = *(const bf16x8*)&sV[vt * 16 + llo][kc * 32 + lhi * 8];
      oacc[vt] = MFMA16(pa, vb, oacc[vt]);
    }
  }

  // write fp32 output
#pragma unroll
  for (int vt = 0; vt < 8; ++vt) {
#pragma unroll
    for (int r = 0; r < 4; ++r) {
      int qq = q0w + lhi * 4 + r;
      if (qq < T_) out[((size_t)b * T_ + qq) * DK + vt * 16 + llo] = oacc[vt][r];
    }
  }
}

extern "C" void kernel_launch(void* const* d_in, const int* in_sizes, int n_in,
                              void* d_out, int out_size, void* d_ws, size_t ws_size,
                              hipStream_t stream) {
  const float* q    = (const float*)d_in[0];
  const int*   padm = (const int*)d_in[1];
  const float* Wq   = (const float*)d_in[2];
  const float* Wk   = (const float*)d_in[3];
  const float* Wv   = (const float*)d_in[4];
  float* out        = (float*)d_out;

  char* ws = (char*)d_ws;
  __bf16* Wcat = (__bf16*)(ws + OFF_W);
  __bf16* Qb   = (__bf16*)(ws + OFF_Q);
  __bf16* Kb   = (__bf16*)(ws + OFF_K);
  __bf16* Vtb  = (__bf16*)(ws + OFF_V);

  wconv_kernel<<<768, 256, 0, stream>>>(Wq, Wk, Wv, Wcat);
  proj_kernel<<<800, 256, 0, stream>>>(q, Wcat, Qb, Kb, Vtb);
  attn_kernel<0><<<256, 256, 0, stream>>>(Qb, Kb, Vtb, padm, out);
  attn_kernel<1><<<256, 256, 0, stream>>>(Qb, Kb, Vtb, padm, out);
  attn_kernel<2><<<256, 256, 0, stream>>>(Qb, Kb, Vtb, padm, out);
  attn_kernel<3><<<256, 256, 0, stream>>>(Qb, Kb, Vtb, padm, out);
}

// Round 8
// 232.217 us; speedup vs baseline: 2.4414x; 1.1188x over previous
//
#include <hip/hip_runtime.h>

typedef __bf16 bf16x8 __attribute__((ext_vector_type(8)));
typedef __bf16 bf16x4 __attribute__((ext_vector_type(4)));
typedef float  f32x4  __attribute__((ext_vector_type(4)));

#define MFMA16(a,b,c) __builtin_amdgcn_mfma_f32_16x16x32_bf16((a),(b),(c),0,0,0)

constexpr int B_ = 256, T_ = 200, DM = 2048, DK = 128;
constexpr int VT_STRIDE = 208;      // Vt[b][v][t], t padded 200->208

// ws layout (bytes)
constexpr size_t OFF_W = 0;                       // Wcat bf16 [384][2048] = 1,572,864
constexpr size_t OFF_Q = 1572864;                 // Q bf16 [51200][128] = 13,107,200
constexpr size_t OFF_K = OFF_Q + 13107200;        // K bf16 [51200][128]
constexpr size_t OFF_V = OFF_K + 13107200;        // Vt bf16 [256][128][208] = 13,631,488

#define GLOAD_LDS16(G, L)                                                     \
  __builtin_amdgcn_global_load_lds(                                           \
      (const __attribute__((address_space(1))) void*)(G),                     \
      (__attribute__((address_space(3))) void*)(L), 16, 0, 0)

// ---------------- weight conversion: Wq|Wk|Wv fp32 -> Wcat bf16 [384][2048] ----------------
__global__ __launch_bounds__(256) void wconv_kernel(const float* __restrict__ Wq,
                                                    const float* __restrict__ Wk,
                                                    const float* __restrict__ Wv,
                                                    __bf16* __restrict__ Wcat) {
  int idx = (blockIdx.x * 256 + threadIdx.x) * 4;   // < 384*2048 = 786432
  int sel = idx >> 18;                              // /262144 -> 0,1,2
  const float* base = (sel == 0) ? Wq : (sel == 1) ? Wk : Wv;
  float4 f = *(const float4*)(base + (idx - (sel << 18)));
  bf16x4 o;
  o[0] = (__bf16)f.x; o[1] = (__bf16)f.y; o[2] = (__bf16)f.z; o[3] = (__bf16)f.w;
  *(bf16x4*)(Wcat + idx) = o;
}

// ---------------- projection GEMM: C[51200][384] = q(fp32->bf16) @ Wcat^T ----------------
// BM=128, BN=384 (full N -> q HBM-read exactly once), BK=32, 512 threads (8 waves 2m x 4n,
// wave tile 64x96, acc=96 AGPR). TRIPLE-buffered global_load_lds staging with COUNTED
// vmcnt (T4): per iter t -> STAGE(t+2); s_waitcnt vmcnt(10) (waits only tile t, issued
// 2 iterations = ~1900cy ago; t+1/t+2's 10 loads stay in flight ACROSS the barrier);
// raw s_barrier (no vm drain); COMPUTE(t); lgkmcnt(0)+s_barrier (WAR). No __syncthreads.
// Both-sides XOR swizzle via pre-swizzled global source (rule #21):
//   A slot(row,cs) holds chunk cs^(row&7); B slot(row,cs) holds kc cs^((row>>1)&3);
// frag reads apply the same XOR -> 2-way aliasing (free). LDS 120 KB -> 1 block/CU.
__global__ __launch_bounds__(512) void proj_kernel(const float* __restrict__ q,
                                                   const __bf16* __restrict__ Wcat,
                                                   __bf16* __restrict__ Qo,
                                                   __bf16* __restrict__ Ko,
                                                   __bf16* __restrict__ Vt) {
  __shared__ alignas(16) char smem[122880];  // 3 bufs x (A fp32 [128][32]=16KB @0, B bf16 [384][32]=24KB @16384)

  const int tid  = threadIdx.x;
  const int lane = tid & 63;
  const int w    = tid >> 6;
  const int wm   = w >> 2, wn = w & 3;       // 2 waves over M, 4 over N
  const int lhi  = lane >> 4, llo = lane & 15;
  const int m0   = blockIdx.x * 128;

  f32x4 acc[4][6];
#pragma unroll
  for (int i = 0; i < 4; ++i)
#pragma unroll
    for (int j = 0; j < 6; ++j) acc[i][j] = {0.f, 0.f, 0.f, 0.f};

  // A staging: 2 rounds of 64 rows; slot s=tid+512r -> row=(tid>>3)+64r, slot-chunk cs=tid&7,
  // global chunk = cs ^ (row&7) = (tid&7)^((tid>>3)&7)   (round-invariant: row&7 fixed)
  const float* agbase = q + (size_t)(m0 + (tid >> 3)) * DM
                          + (((tid & 7) ^ ((tid >> 3) & 7)) << 2);
  // B staging: 3 rounds of 128 rows; s=tid+512r -> row=(tid>>2)+128r, slot kc=tid&3,
  // global kc = (tid&3) ^ ((row>>1)&3) = (tid&3)^((tid>>3)&3)   (round-invariant)
  const __bf16* bgbase = Wcat + (size_t)(tid >> 2) * DM
                              + (((tid & 3) ^ ((tid >> 3) & 3)) << 3);

#define STAGE(LB, K0)                                                         \
  {                                                                           \
    char* la_ = (LB);                                                         \
    char* lb_ = la_ + 16384;                                                  \
    _Pragma("unroll")                                                         \
    for (int r = 0; r < 2; ++r)                                               \
      GLOAD_LDS16(agbase + (size_t)r * 64 * DM + (K0), la_ + tid * 16 + r * 8192); \
    _Pragma("unroll")                                                         \
    for (int r = 0; r < 3; ++r)                                               \
      GLOAD_LDS16(bgbase + (size_t)r * 128 * DM + (K0), lb_ + tid * 16 + r * 8192); \
  }

#define COMPUTE(LB)                                                           \
  {                                                                           \
    const char* la_ = (LB);                                                   \
    const char* lb_ = la_ + 16384;                                            \
    bf16x8 af[4];                                                             \
    _Pragma("unroll")                                                         \
    for (int i = 0; i < 4; ++i) {                                             \
      const int row = wm * 64 + i * 16 + llo;                                 \
      f32x4 u = *(const f32x4*)(la_ + row * 128 + (((2 * lhi) ^ (llo & 7)) << 4));     \
      f32x4 v = *(const f32x4*)(la_ + row * 128 + (((2 * lhi + 1) ^ (llo & 7)) << 4)); \
      af[i][0]=(__bf16)u[0]; af[i][1]=(__bf16)u[1]; af[i][2]=(__bf16)u[2]; af[i][3]=(__bf16)u[3]; \
      af[i][4]=(__bf16)v[0]; af[i][5]=(__bf16)v[1]; af[i][6]=(__bf16)v[2]; af[i][7]=(__bf16)v[3]; \
    }                                                                         \
    bf16x8 bfr[6];                                                            \
    _Pragma("unroll")                                                         \
    for (int j = 0; j < 6; ++j) {                                             \
      const int row = wn * 96 + j * 16 + llo;                                 \
      bfr[j] = *(const bf16x8*)(lb_ + row * 64 + ((lhi ^ ((llo >> 1) & 3)) << 4)); \
    }                                                                         \
    _Pragma("unroll")                                                         \
    for (int i = 0; i < 4; ++i)                                               \
      _Pragma("unroll")                                                       \
      for (int j = 0; j < 6; ++j) acc[i][j] = MFMA16(af[i], bfr[j], acc[i][j]); \
  }

  constexpr int NK = DM / 32;   // 64 K-steps
  STAGE(smem, 0);
  STAGE(smem + 40960, 32);

  int cur = 0;
  for (int t = 0; t < NK; ++t) {
    if (t + 2 < NK) {
      int sb = cur + 2; if (sb >= 3) sb -= 3;
      STAGE(smem + sb * 40960, (t + 2) * 32);
      asm volatile("s_waitcnt vmcnt(10)" ::: "memory");   // tile t landed; 10 newest stay in flight
      __builtin_amdgcn_s_barrier();
    } else if (t + 2 == NK) {
      asm volatile("s_waitcnt vmcnt(5)" ::: "memory");    // tile NK-2 landed
      __builtin_amdgcn_s_barrier();
    } else {
      asm volatile("s_waitcnt vmcnt(0)" ::: "memory");    // tile NK-1 landed
      __builtin_amdgcn_s_barrier();
    }
    COMPUTE(smem + cur * 40960);
    asm volatile("s_waitcnt lgkmcnt(0)" ::: "memory");    // ds_reads done before buf reuse
    __builtin_amdgcn_s_barrier();                         // WAR: no vm drain here
    cur = cur + 1; if (cur >= 3) cur -= 3;
  }
#undef STAGE
#undef COMPUTE

  // epilogue: col<128 -> Q, <256 -> K, else -> Vt transposed per batch
#pragma unroll
  for (int i = 0; i < 4; ++i) {
#pragma unroll
    for (int r = 0; r < 4; ++r) {
      int row = m0 + wm * 64 + i * 16 + lhi * 4 + r;   // bt index, always < 51200
      int b = row / 200;
      int t = row - b * 200;
#pragma unroll
      for (int j = 0; j < 6; ++j) {
        int col = wn * 96 + j * 16 + llo;
        __bf16 bv = (__bf16)acc[i][j][r];
        if (col < 128)       Qo[(size_t)row * DK + col] = bv;
        else if (col < 256)  Ko[(size_t)row * DK + (col - 128)] = bv;
        else                 Vt[((size_t)b * DK + (col - 256)) * VT_STRIDE + t] = bv;
      }
    }
  }
}

// ---------------- attention: one WG per (batch, 64-query block), templated on block ----------------
template <int QB>
__global__ __launch_bounds__(256, 1) void attn_kernel(const __bf16* __restrict__ Qg,
                                                      const __bf16* __restrict__ Kg,
                                                      const __bf16* __restrict__ Vt,
                                                      const int* __restrict__ padm,
                                                      float* __restrict__ out) {
  constexpr int Q0     = QB * 64;
  constexpr int KMAX   = (Q0 + 64 < T_) ? (Q0 + 64) : T_;   // 64,128,192,200 (causal bound)
  constexpr int KTILES = (KMAX + 15) / 16;                  // 4,8,12,13
  constexpr int KCC    = (KMAX + 31) / 32;                  // 2,4,6,7
  constexpr int KT16   = KTILES * 16;                       // 64,128,192,208
  constexpr int KP     = KCC * 32;                          // 64,128,192,224
  constexpr int VS     = KP + 8;                            // padded stride (bank spread)

  __shared__ __bf16 sK[KT16][136];
  __shared__ __bf16 sV[128][VS];       // V^T: [v][t]
  __shared__ __bf16 sP[4][16][VS];     // per-wave P transpose buffer
  __shared__ float  sMask[KT16];

  const int tid  = threadIdx.x;
  const int lane = tid & 63;
  const int w    = tid >> 6;
  const int b    = blockIdx.x;
  const int lhi  = lane >> 4, llo = lane & 15;

  // additive key mask: 0 valid, -1e30 for pad / t>=KMAX
  for (int t = tid; t < KT16; t += 256) {
    float mv = -1e30f;
    if (t < KMAX && padm[b * T_ + t] == 0) mv = 0.0f;
    sMask[t] = mv;
  }
  // stage K rows [0, KT16) (rows >= T_ clamped; they get masked anyway)
  for (int cid = tid; cid < KT16 * 16; cid += 256) {
    int t = cid >> 4, c = (cid & 15) * 8;
    int tg = (t < T_) ? t : (T_ - 1);
    *(bf16x8*)&sK[t][c] = *(const bf16x8*)(Kg + ((size_t)b * T_ + tg) * DK + c);
  }
  // stage V^T: [128][KP), zeros beyond Vt's 208 columns
  {
    constexpr int NCH = KP / 8;
    for (int cid = tid; cid < 128 * NCH; cid += 256) {
      int v = cid / NCH, t0 = (cid % NCH) * 8;
      bf16x8 val;
      if (t0 < VT_STRIDE) {
        val = *(const bf16x8*)(Vt + ((size_t)b * DK + v) * VT_STRIDE + t0);
      } else {
#pragma unroll
        for (int jz = 0; jz < 8; ++jz) val[jz] = (__bf16)0.0f;
      }
      *(bf16x8*)&sV[v][t0] = val;
    }
  }
  // zero P pad columns [KT16, KP) (only QB==3: 208..224)
  if constexpr (KT16 < KP) {
    constexpr int NC = (KP - KT16) / 8;
    for (int idx = tid; idx < 4 * 16 * NC; idx += 256) {
      int ww = idx / (16 * NC);
      int rem = idx % (16 * NC);
      int row = rem / NC, cc = (rem % NC) * 8;
      bf16x8 z;
#pragma unroll
      for (int jz = 0; jz < 8; ++jz) z[jz] = (__bf16)0.0f;
      *(bf16x8*)&sP[ww][row][KT16 + cc] = z;
    }
  }
  __syncthreads();

  // Q fragments in registers (A-frag: row = llo, k-chunk = lhi)
  const int q0w = Q0 + w * 16;
  bf16x8 qf[4];
  {
    int qrow = q0w + llo;
    if (qrow > T_ - 1) qrow = T_ - 1;
    const __bf16* qp = Qg + ((size_t)b * T_ + qrow) * DK + lhi * 8;
#pragma unroll
    for (int kk = 0; kk < 4; ++kk) qf[kk] = *(const bf16x8*)(qp + kk * 32);
  }

  // scores: S[16q x KT16] per wave, kept in registers
  float sc[KTILES][4];
  const float scale = 0.022097086912079608f;   // 1/sqrt(2048)
#pragma unroll
  for (int tt = 0; tt < KTILES; ++tt) {
    f32x4 s = {0.f, 0.f, 0.f, 0.f};
    const __bf16* kp = &sK[tt * 16 + llo][lhi * 8];
#pragma unroll
    for (int kk = 0; kk < 4; ++kk) {
      bf16x8 kf = *(const bf16x8*)(kp + kk * 32);
      s = MFMA16(qf[kk], kf, s);
    }
    const int t = tt * 16 + llo;
    const float madd = sMask[t];
#pragma unroll
    for (int r = 0; r < 4; ++r) {
      int qq = q0w + lhi * 4 + r;               // C layout: row = lhi*4+r, col = llo
      float v = fmaf(s[r], scale, madd);
      sc[tt][r] = (t > qq) ? -1e30f : v;        // overwrite-style causal mask (NaN-safe)
    }
  }

  // row softmax: reduce across the 16-lane col group per accumulator row
#pragma unroll
  for (int r = 0; r < 4; ++r) {
    float mm = -3e38f;
#pragma unroll
    for (int tt = 0; tt < KTILES; ++tt) mm = fmaxf(mm, sc[tt][r]);
#pragma unroll
    for (int off = 1; off < 16; off <<= 1) mm = fmaxf(mm, __shfl_xor(mm, off));
    float ss = 0.f;
#pragma unroll
    for (int tt = 0; tt < KTILES; ++tt) { float e = __expf(sc[tt][r] - mm); sc[tt][r] = e; ss += e; }
#pragma unroll
    for (int off = 1; off < 16; off <<= 1) ss += __shfl_xor(ss, off);
    float inv = 1.0f / ss;
#pragma unroll
    for (int tt = 0; tt < KTILES; ++tt) sc[tt][r] *= inv;
  }

  // P -> LDS (transpose through memory for the PV A-fragment)
#pragma unroll
  for (int tt = 0; tt < KTILES; ++tt) {
    int t = tt * 16 + llo;
#pragma unroll
    for (int r = 0; r < 4; ++r) sP[w][lhi * 4 + r][t] = (__bf16)sc[tt][r];
  }
  __syncthreads();

  // PV: out[16q x 128v] = P[16 x KP] @ V[KP x 128]
  f32x4 oacc[8];
#pragma unroll
  for (int vt = 0; vt < 8; ++vt) oacc[vt] = {0.f, 0.f, 0.f, 0.f};
#pragma unroll
  for (int kc = 0; kc < KCC; ++kc) {
    bf16x8 pa = *(const bf16x8*)&sP[w][llo][kc * 32 + lhi * 8];
#pragma unroll
    for (int vt = 0; vt < 8; ++vt) {
      bf16x8 vb = *(const bf16x8*)&sV[vt * 16 + llo][kc * 32 + lhi * 8];
      oacc[vt] = MFMA16(pa, vb, oacc[vt]);
    }
  }

  // write fp32 output
#pragma unroll
  for (int vt = 0; vt < 8; ++vt) {
#pragma unroll
    for (int r = 0; r < 4; ++r) {
      int qq = q0w + lhi * 4 + r;
      if (qq < T_) out[((size_t)b * T_ + qq) * DK + vt * 16 + llo] = oacc[vt][r];
    }
  }
}

extern "C" void kernel_launch(void* const* d_in, const int* in_sizes, int n_in,
                              void* d_out, int out_size, void* d_ws, size_t ws_size,
                              hipStream_t stream) {
  const float* q    = (const float*)d_in[0];
  const int*   padm = (const int*)d_in[1];
  const float* Wq   = (const float*)d_in[2];
  const float* Wk   = (const float*)d_in[3];
  const float* Wv   = (const float*)d_in[4];
  float* out        = (float*)d_out;

  char* ws = (char*)d_ws;
  __bf16* Wcat = (__bf16*)(ws + OFF_W);
  __bf16* Qb   = (__bf16*)(ws + OFF_Q);
  __bf16* Kb   = (__bf16*)(ws + OFF_K);
  __bf16* Vtb  = (__bf16*)(ws + OFF_V);

  wconv_kernel<<<768, 256, 0, stream>>>(Wq, Wk, Wv, Wcat);
  proj_kernel<<<400, 512, 0, stream>>>(q, Wcat, Qb, Kb, Vtb);
  attn_kernel<0><<<256, 256, 0, stream>>>(Qb, Kb, Vtb, padm, out);
  attn_kernel<1><<<256, 256, 0, stream>>>(Qb, Kb, Vtb, padm, out);
  attn_kernel<2><<<256, 256, 0, stream>>>(Qb, Kb, Vtb, padm, out);
  attn_kernel<3><<<256, 256, 0, stream>>>(Qb, Kb, Vtb, padm, out);
}